// Round 8
// baseline (809.483 us; speedup 1.0000x reference)
//
#include <hip/hip_runtime.h>
#include <math.h>

static constexpr int IN_D = 256;
static constexpr int HIDD = 128;

// ---------------------------------------------------------------------------
// init: zero histograms and the f64 stat block (256 doubles)
__global__ void init_kernel(int* __restrict__ hist, int* __restrict__ odeg,
                            double* __restrict__ dsum, int n) {
    int i = blockIdx.x * 256 + threadIdx.x;
    if (i < n) { hist[i] = 0; odeg[i] = 0; }
    if (i < 256) dsum[i] = 0.0;
}

__global__ void hist_kernel(const int* __restrict__ src, const int* __restrict__ dst,
                            int* __restrict__ hist, int* __restrict__ odeg, int E) {
    int e = blockIdx.x * 256 + threadIdx.x;
    if (e < E) {
        atomicAdd(&hist[dst[e]], 1);
        atomicAdd(&odeg[src[e]], 1);
    }
}

// Single-block exclusive scan over hist[N] -> rowptr/cursor; dinv = rsqrt(deg+1)
__global__ __launch_bounds__(1024)
void scan_kernel(const int* __restrict__ hist, int* __restrict__ rowptr,
                 int* __restrict__ cursor, float* __restrict__ dinv, int N, int E) {
    __shared__ int lsum[1024];
    const int t = threadIdx.x;
    const int chunk = (N + 1023) >> 10;
    const int lo = t * chunk;
    const int hi = min(N, lo + chunk);
    int s = 0;
    for (int i = lo; i < hi; i++) s += hist[i];
    lsum[t] = s;
    __syncthreads();
    for (int off = 1; off < 1024; off <<= 1) {
        int v = (t >= off) ? lsum[t - off] : 0;
        __syncthreads();
        lsum[t] += v;
        __syncthreads();
    }
    int run = lsum[t] - s;  // exclusive prefix
    for (int i = lo; i < hi; i++) {
        rowptr[i] = run;
        cursor[i] = run;
        dinv[i] = rsqrtf((float)hist[i] + 1.0f);  // +1 self-loop
        run += hist[i];
    }
    if (t == 1023) rowptr[N] = E;
}

__global__ void fill_kernel(const int* __restrict__ src, const int* __restrict__ dst,
                            int* __restrict__ cursor, int* __restrict__ ssort,
                            int* __restrict__ dsort, int* __restrict__ esort, int E) {
    int e = blockIdx.x * 256 + threadIdx.x;
    if (e < E) {
        int d = dst[e];
        int pos = atomicAdd(&cursor[d], 1);
        ssort[pos] = src[e];
        dsort[pos] = d;
        esort[pos] = e;
    }
}

// ---------------------------------------------------------------------------
// Generic tiled f32 GEMM: C[M,NCOL] = op(A[M,K]) @ W[K,NCOL] (+ bias)
template <int K, int NCOL, bool RELU, bool BIAS>
__global__ __launch_bounds__((NCOL / 4) * 16)
void mm_kernel(const float* __restrict__ A, const float* __restrict__ W,
               const float* __restrict__ bias, float* __restrict__ C, int M) {
    constexpr int MT = 64;
    constexpr int KK = 32;
    constexpr int TPB = (NCOL / 4) * (MT / 4);
    __shared__ float xs[KK][MT + 4];
    __shared__ float ws[KK][NCOL];

    const int t = threadIdx.x;
    const int m0 = blockIdx.x * MT;
    const int tc = t % (NCOL / 4);
    const int tr = t / (NCOL / 4);
    const int c0 = tc * 4, r0 = tr * 4;

    float acc[4][4] = {};

    for (int ko = 0; ko < K; ko += KK) {
        constexpr int NF4 = MT * KK / 4;
        for (int idx = t; idx < NF4; idx += TPB) {
            int m = idx >> 3;
            int jk = idx & 7;
            float4 v = make_float4(0.f, 0.f, 0.f, 0.f);
            if (m0 + m < M)
                v = *(const float4*)&A[(size_t)(m0 + m) * K + ko + jk * 4];
            if (RELU) {
                v.x = fmaxf(v.x, 0.f); v.y = fmaxf(v.y, 0.f);
                v.z = fmaxf(v.z, 0.f); v.w = fmaxf(v.w, 0.f);
            }
            xs[jk * 4 + 0][m] = v.x;
            xs[jk * 4 + 1][m] = v.y;
            xs[jk * 4 + 2][m] = v.z;
            xs[jk * 4 + 3][m] = v.w;
        }
        constexpr int WF4 = KK * NCOL / 4;
        const float4* Wp = (const float4*)(W + (size_t)ko * NCOL);
        float4* wsp = (float4*)&ws[0][0];
        for (int idx = t; idx < WF4; idx += TPB) wsp[idx] = Wp[idx];
        __syncthreads();

#pragma unroll
        for (int kk = 0; kk < KK; kk++) {
            float4 av = *(const float4*)&xs[kk][r0];
            float4 wv = *(const float4*)&ws[kk][c0];
            acc[0][0] += av.x * wv.x; acc[0][1] += av.x * wv.y;
            acc[0][2] += av.x * wv.z; acc[0][3] += av.x * wv.w;
            acc[1][0] += av.y * wv.x; acc[1][1] += av.y * wv.y;
            acc[1][2] += av.y * wv.z; acc[1][3] += av.y * wv.w;
            acc[2][0] += av.z * wv.x; acc[2][1] += av.z * wv.y;
            acc[2][2] += av.z * wv.z; acc[2][3] += av.z * wv.w;
            acc[3][0] += av.w * wv.x; acc[3][1] += av.w * wv.y;
            acc[3][2] += av.w * wv.z; acc[3][3] += av.w * wv.w;
        }
        __syncthreads();
    }

    float4 b4 = make_float4(0.f, 0.f, 0.f, 0.f);
    if (BIAS) b4 = *(const float4*)&bias[c0];
#pragma unroll
    for (int i = 0; i < 4; i++) {
        int row = m0 + r0 + i;
        if (row < M) {
            float4 o;
            o.x = acc[i][0] + b4.x; o.y = acc[i][1] + b4.y;
            o.z = acc[i][2] + b4.z; o.w = acc[i][3] + b4.w;
            *(float4*)&C[(size_t)row * NCOL + c0] = o;
        }
    }
}

// ---------------------------------------------------------------------------
// CSR gather aggregation: agg[n][c] = hW[n][c]*dinv[n]^2 + b[c]
//                                   + sum_{s in in(n)} hW[s][c]*dinv[s]*dinv[n]
template <int NC>
__global__ __launch_bounds__(256)
void agg_kernel(const float* __restrict__ hW, const float* __restrict__ dinv,
                const int* __restrict__ rowptr, const int* __restrict__ src_sorted,
                const float* __restrict__ b, float* __restrict__ agg, int N) {
    constexpr int TPN = NC / 4;
    constexpr int NPB = 256 / TPN;
    const int t = threadIdx.x;
    const int node = blockIdx.x * NPB + t / TPN;
    if (node >= N) return;
    const int c4 = (t % TPN) * 4;

    const float dn = dinv[node];
    float4 h = *(const float4*)&hW[(size_t)node * NC + c4];
    float4 bb = *(const float4*)&b[c4];
    float4 acc;
    acc.x = h.x * dn * dn + bb.x;
    acc.y = h.y * dn * dn + bb.y;
    acc.z = h.z * dn * dn + bb.z;
    acc.w = h.w * dn * dn + bb.w;

    const int i1 = rowptr[node + 1];
    for (int i = rowptr[node]; i < i1; i++) {
        int s = src_sorted[i];
        float w = dinv[s] * dn;
        float4 v = *(const float4*)&hW[(size_t)s * NC + c4];
        acc.x += v.x * w; acc.y += v.y * w; acc.z += v.z * w; acc.w += v.w * w;
    }
    *(float4*)&agg[(size_t)node * NC + c4] = acc;
}

// ---------------------------------------------------------------------------
// Build Wc[64][128] = [W_m0_top | W_m0_bot]
__global__ void concat_w_kernel(const float* __restrict__ Wm0, float* __restrict__ Wc) {
    int i = blockIdx.x * 256 + threadIdx.x;
    if (i < 64 * 128) {
        int k = i >> 7, j = i & 127;
        Wc[i] = (j < 64) ? Wm0[k * 64 + j] : Wm0[(64 + k) * 64 + (j - 64)];
    }
}

// ---------------------------------------------------------------------------
// BN0 stats via node-level algebra (replaces the O(E) z0stats pass).
// dS1[c] = sum_n odeg*A + ideg*B ; dS2[c] = sum_n odeg*A^2 + ideg*B^2 ;
// dX[c]  = sum_e A[src][c]*B[dst][c] = sum_d B[d][c] * (sum_{s in in(d)} A[s][c])
__global__ __launch_bounds__(256)
void bn0_node_kernel(const float* __restrict__ AB, const int* __restrict__ ideg,
                     const int* __restrict__ odeg, const int* __restrict__ rowptr,
                     const int* __restrict__ ssort,
                     double* __restrict__ dS1, double* __restrict__ dS2,
                     double* __restrict__ dX, int N) {
    const int t = threadIdx.x;
    const int c4 = (t & 15) * 4;
    const int slot = t >> 4;  // 16 node-slots per block
    float rS1[4] = {}, rS2[4] = {}, rX[4] = {};

    for (int n = blockIdx.x * 16 + slot; n < N; n += gridDim.x * 16) {
        float od = (float)odeg[n];
        float id = (float)ideg[n];
        float4 A4 = *(const float4*)&AB[(size_t)n * 128 + c4];
        float4 B4 = *(const float4*)&AB[(size_t)n * 128 + 64 + c4];
        float4 ca = make_float4(0.f, 0.f, 0.f, 0.f);
        const int i1 = rowptr[n + 1];
        for (int i = rowptr[n]; i < i1; i++) {
            int s = ssort[i];
            float4 v = *(const float4*)&AB[(size_t)s * 128 + c4];
            ca.x += v.x; ca.y += v.y; ca.z += v.z; ca.w += v.w;
        }
        rS1[0] += od * A4.x + id * B4.x;
        rS1[1] += od * A4.y + id * B4.y;
        rS1[2] += od * A4.z + id * B4.z;
        rS1[3] += od * A4.w + id * B4.w;
        rS2[0] += od * A4.x * A4.x + id * B4.x * B4.x;
        rS2[1] += od * A4.y * A4.y + id * B4.y * B4.y;
        rS2[2] += od * A4.z * A4.z + id * B4.z * B4.z;
        rS2[3] += od * A4.w * A4.w + id * B4.w * B4.w;
        rX[0] += ca.x * B4.x; rX[1] += ca.y * B4.y;
        rX[2] += ca.z * B4.z; rX[3] += ca.w * B4.w;
    }

    __shared__ float m1[16][64], m2[16][64], mx[16][64];
#pragma unroll
    for (int i = 0; i < 4; i++) {
        m1[slot][c4 + i] = rS1[i];
        m2[slot][c4 + i] = rS2[i];
        mx[slot][c4 + i] = rX[i];
    }
    __syncthreads();
    if (t < 64) {
        float a1 = 0.f, a2 = 0.f, ax = 0.f;
#pragma unroll
        for (int q = 0; q < 16; q++) { a1 += m1[q][t]; a2 += m2[q][t]; ax += mx[q][t]; }
        atomicAdd(&dS1[t], (double)a1);
        atomicAdd(&dS2[t], (double)a2);
        atomicAdd(&dX[t], (double)ax);
    }
}

// mean = S1/E + bm ; var = (S2 + 2X)/E - (S1/E)^2  (bm terms cancel in var)
__global__ void bnprep0_kernel(const double* __restrict__ dS1, const double* __restrict__ dS2,
                               const double* __restrict__ dX,
                               const float* __restrict__ g, const float* __restrict__ be,
                               const float* __restrict__ bm,
                               float* __restrict__ s0, float* __restrict__ t0, int E) {
    int c = threadIdx.x;
    if (c < 64) {
        double a1 = dS1[c] / (double)E;
        double var = (dS2[c] + 2.0 * dX[c]) / (double)E - a1 * a1;
        double mean = a1 + (double)bm[c];
        double inv = 1.0 / sqrt(var + 1e-5);
        float s = (float)((double)g[c] * inv);
        float t = (float)((double)be[c] - (double)s * mean);
        s0[c] = s; t0[c] = t;
    }
}

// ---------------------------------------------------------------------------
// MLP layer 1 as an edge-tile GEMM (TE=256, 512 threads), BN1 stats fused.
// Stats LDS overlays the dead yt buffer after the GEMM.
__global__ __launch_bounds__(512)
void mlp1_fused_kernel(const float* __restrict__ AB, const int* __restrict__ ssort,
                       const int* __restrict__ dsort, const float* __restrict__ bm0v,
                       const float* __restrict__ s0v, const float* __restrict__ t0v,
                       const float* __restrict__ Wm1, const float* __restrict__ bm1,
                       float* __restrict__ z1, double* __restrict__ st, int E) {
    constexpr int TE = 256;
    __shared__ float smem[64 * TE];      // yt[k][e], later ls1/ls2
    __shared__ float wls[64 * 32];
    __shared__ float svls[64], tvls[64], bmls[64], b1ls[32];

    const int t = threadIdx.x;
    for (int i = t; i < 2048; i += 512) wls[i] = Wm1[i];
    if (t < 64) { svls[t] = s0v[t]; tvls[t] = t0v[t]; bmls[t] = bm0v[t]; }
    if (t < 32) b1ls[t] = bm1[t];
    __syncthreads();

    // ---- stage: 2 threads per edge, each covers 32 channels ----
    const int base = blockIdx.x * TE;
    const int le = t >> 1, half = t & 1;
    const int pos = base + le;
    if (pos < E) {
        const int s = ssort[pos], d = dsort[pos];
        const float* Ar = AB + (size_t)s * 128;
        const float* Br = AB + (size_t)d * 128 + 64;
#pragma unroll
        for (int q = 0; q < 8; q++) {
            int c = half * 32 + q * 4;
            float4 a = *(const float4*)&Ar[c];
            float4 b = *(const float4*)&Br[c];
            float4 sv = *(const float4*)&svls[c];
            float4 tv = *(const float4*)&tvls[c];
            float4 mv = *(const float4*)&bmls[c];
            smem[(c + 0) * TE + le] = fmaxf(sv.x * (a.x + b.x + mv.x) + tv.x, 0.f);
            smem[(c + 1) * TE + le] = fmaxf(sv.y * (a.y + b.y + mv.y) + tv.y, 0.f);
            smem[(c + 2) * TE + le] = fmaxf(sv.z * (a.z + b.z + mv.z) + tv.z, 0.f);
            smem[(c + 3) * TE + le] = fmaxf(sv.w * (a.w + b.w + mv.w) + tv.w, 0.f);
        }
    } else {
#pragma unroll
        for (int q = 0; q < 8; q++) {
            int c = half * 32 + q * 4;
            smem[(c + 0) * TE + le] = 0.f; smem[(c + 1) * TE + le] = 0.f;
            smem[(c + 2) * TE + le] = 0.f; smem[(c + 3) * TE + le] = 0.f;
        }
    }
    __syncthreads();

    // ---- GEMM: out tile 256 edges x 32 cols, 4x4 per thread ----
    const int tr = t >> 3, tc = t & 7;   // tr 0..63, tc 0..7
    const int r0 = tr * 4, c0 = tc * 4;
    float acc[4][4];
#pragma unroll
    for (int i = 0; i < 4; i++) {
        acc[i][0] = b1ls[c0 + 0]; acc[i][1] = b1ls[c0 + 1];
        acc[i][2] = b1ls[c0 + 2]; acc[i][3] = b1ls[c0 + 3];
    }
#pragma unroll 8
    for (int kk = 0; kk < 64; kk++) {
        float4 av = *(const float4*)&smem[kk * TE + r0];
        float4 wv = *(const float4*)&wls[kk * 32 + c0];
        acc[0][0] += av.x * wv.x; acc[0][1] += av.x * wv.y;
        acc[0][2] += av.x * wv.z; acc[0][3] += av.x * wv.w;
        acc[1][0] += av.y * wv.x; acc[1][1] += av.y * wv.y;
        acc[1][2] += av.y * wv.z; acc[1][3] += av.y * wv.w;
        acc[2][0] += av.z * wv.x; acc[2][1] += av.z * wv.y;
        acc[2][2] += av.z * wv.z; acc[2][3] += av.z * wv.w;
        acc[3][0] += av.w * wv.x; acc[3][1] += av.w * wv.y;
        acc[3][2] += av.w * wv.z; acc[3][3] += av.w * wv.w;
    }

    // ---- z1 write + local BN1 stats ----
    float cs1[4] = {0.f, 0.f, 0.f, 0.f};
    float cs2[4] = {0.f, 0.f, 0.f, 0.f};
#pragma unroll
    for (int i = 0; i < 4; i++) {
        int pz = base + r0 + i;
        if (pz < E) {
            float4 o;
            o.x = acc[i][0]; o.y = acc[i][1]; o.z = acc[i][2]; o.w = acc[i][3];
            *(float4*)&z1[(size_t)pz * 32 + c0] = o;
            cs1[0] += o.x; cs1[1] += o.y; cs1[2] += o.z; cs1[3] += o.w;
            cs2[0] += o.x * o.x; cs2[1] += o.y * o.y;
            cs2[2] += o.z * o.z; cs2[3] += o.w * o.w;
        }
    }
    __syncthreads();                 // yt dead -> overlay stats
    float* ls1 = smem;
    float* ls2 = smem + 64 * 32;
    ls1[tr * 32 + c0 + 0] = cs1[0]; ls1[tr * 32 + c0 + 1] = cs1[1];
    ls1[tr * 32 + c0 + 2] = cs1[2]; ls1[tr * 32 + c0 + 3] = cs1[3];
    ls2[tr * 32 + c0 + 0] = cs2[0]; ls2[tr * 32 + c0 + 1] = cs2[1];
    ls2[tr * 32 + c0 + 2] = cs2[2]; ls2[tr * 32 + c0 + 3] = cs2[3];
    __syncthreads();
    if (t < 32) {
        float a1 = 0.f, a2 = 0.f;
#pragma unroll
        for (int r = 0; r < 64; r++) { a1 += ls1[r * 32 + t]; a2 += ls2[r * 32 + t]; }
        atomicAdd(&st[t], (double)a1);
        atomicAdd(&st[32 + t], (double)a2);
    }
}

__global__ void bnprep1_kernel(const double* __restrict__ st,
                               const float* __restrict__ g, const float* __restrict__ be,
                               float* __restrict__ s1, float* __restrict__ t1, int E) {
    int c = threadIdx.x;
    if (c < 32) {
        double mu = st[c] / (double)E;
        double var = st[32 + c] / (double)E - mu * mu;
        double inv = 1.0 / sqrt(var + 1e-5);
        float s = (float)((double)g[c] * inv);
        float t = (float)((double)be[c] - (double)s * mu);
        s1[c] = s; t1[c] = t;
    }
}

// MLP layer 2 + sigmoid; z1 is in sorted order -> scatter out via esort
__global__ void mlp2_kernel(const float* __restrict__ z1, const int* __restrict__ esort,
                            const float* __restrict__ s1, const float* __restrict__ t1,
                            const float* __restrict__ Wm2, const float* __restrict__ bm2,
                            float* __restrict__ out, int E) {
    int pos = blockIdx.x * 256 + threadIdx.x;
    if (pos >= E) return;
    const float* zr = z1 + (size_t)pos * 32;
    float acc = bm2[0];
#pragma unroll
    for (int k = 0; k < 32; k += 4) {
        float4 z4 = *(const float4*)&zr[k];
        float4 sv = *(const float4*)&s1[k];
        float4 tv = *(const float4*)&t1[k];
        float4 wv = *(const float4*)&Wm2[k];
        acc += fmaxf(sv.x * z4.x + tv.x, 0.f) * wv.x;
        acc += fmaxf(sv.y * z4.y + tv.y, 0.f) * wv.y;
        acc += fmaxf(sv.z * z4.z + tv.z, 0.f) * wv.z;
        acc += fmaxf(sv.w * z4.w + tv.w, 0.f) * wv.w;
    }
    out[esort[pos]] = 1.f / (1.f + expf(-acc));
}

// ---------------------------------------------------------------------------
extern "C" void kernel_launch(void* const* d_in, const int* in_sizes, int n_in,
                              void* d_out, int out_size, void* d_ws, size_t ws_size,
                              hipStream_t stream) {
    const float* x      = (const float*)d_in[0];
    const int*   eidx   = (const int*)d_in[1];
    const float* W_emb  = (const float*)d_in[2];
    const float* b_emb  = (const float*)d_in[3];
    const float* W_g1   = (const float*)d_in[4];
    const float* b_g1   = (const float*)d_in[5];
    const float* W_g2   = (const float*)d_in[6];
    const float* b_g2   = (const float*)d_in[7];
    const float* W_m0   = (const float*)d_in[8];
    const float* b_m0   = (const float*)d_in[9];
    const float* g_m0   = (const float*)d_in[10];
    const float* be_m0  = (const float*)d_in[11];
    const float* W_m1   = (const float*)d_in[12];
    const float* b_m1   = (const float*)d_in[13];
    const float* g_m1   = (const float*)d_in[14];
    const float* be_m1  = (const float*)d_in[15];
    const float* W_m2   = (const float*)d_in[16];
    const float* b_m2   = (const float*)d_in[17];
    float* out = (float*)d_out;

    const int N = in_sizes[0] / IN_D;   // 50000
    const int E = in_sizes[1] / 2;      // 800000
    const int* src = eidx;
    const int* dst = eidx + E;

    char* p = (char*)d_ws;
    auto alloc = [&](size_t bytes) {
        void* r = (void*)p;
        p += (bytes + 255) & ~(size_t)255;
        return r;
    };
    int*    hist   = (int*)alloc((size_t)N * 4);            // in-degree (raw)
    int*    odeg   = (int*)alloc((size_t)N * 4);            // out-degree (raw)
    int*    rowptr = (int*)alloc((size_t)(N + 1) * 4);
    int*    cursor = (int*)alloc((size_t)N * 4);
    int*    ssort  = (int*)alloc((size_t)E * 4);
    int*    dsort  = (int*)alloc((size_t)E * 4);
    int*    esort  = (int*)alloc((size_t)E * 4);
    float*  dinv   = (float*)alloc((size_t)N * 4);
    float*  B2     = (float*)alloc((size_t)N * HIDD * 4);   // h0, later agg2
    float*  B3     = (float*)alloc((size_t)N * HIDD * 4);   // hW1, later hW2
    float*  B4     = (float*)alloc((size_t)N * HIDD * 4);   // agg1, later AB
    float*  z1     = (float*)alloc((size_t)E * 32 * 4);
    float*  Wc     = (float*)alloc(64 * 128 * 4);
    double* dsum   = (double*)alloc(256 * 8);               // S1|S2|X|st1
    float*  s0     = (float*)alloc(64 * 4);
    float*  t0     = (float*)alloc(64 * 4);
    float*  s1v    = (float*)alloc(32 * 4);
    float*  t1v    = (float*)alloc(32 * 4);

    double* dS1 = dsum;
    double* dS2 = dsum + 64;
    double* dX  = dsum + 128;
    double* st1 = dsum + 192;

    float* h0   = B2;  float* agg2 = B2;
    float* hW1  = B3;  float* hW2  = B3;
    float* agg1 = B4;  float* AB   = B4;

    const int nbE = (E + 255) / 256;

    // CSR build (dst-sorted) + degrees + dinv
    init_kernel<<<(N + 255) / 256, 256, 0, stream>>>(hist, odeg, dsum, N);
    hist_kernel<<<nbE, 256, 0, stream>>>(src, dst, hist, odeg, E);
    scan_kernel<<<1, 1024, 0, stream>>>(hist, rowptr, cursor, dinv, N, E);
    fill_kernel<<<nbE, 256, 0, stream>>>(src, dst, cursor, ssort, dsort, esort, E);

    // embedding: h0 = x @ W_emb + b_emb
    mm_kernel<256, 128, false, true><<<(N + 63) / 64, 512, 0, stream>>>(x, W_emb, b_emb, h0, N);

    // GCN1
    mm_kernel<128, 128, false, false><<<(N + 63) / 64, 512, 0, stream>>>(h0, W_g1, nullptr, hW1, N);
    agg_kernel<128><<<(N + 7) / 8, 256, 0, stream>>>(hW1, dinv, rowptr, ssort, b_g1, agg1, N);

    // GCN2 (relu on agg1 fused into GEMM staging)
    mm_kernel<128, 64, true, false><<<(N + 63) / 64, 256, 0, stream>>>(agg1, W_g2, nullptr, hW2, N);
    agg_kernel<64><<<(N + 15) / 16, 256, 0, stream>>>(hW2, dinv, rowptr, ssort, b_g2, agg2, N);

    // AB = h2 @ [Wtop|Wbot]  (edge MLP layer-0 factorization)
    concat_w_kernel<<<32, 256, 0, stream>>>(W_m0, Wc);
    mm_kernel<64, 128, false, false><<<(N + 63) / 64, 512, 0, stream>>>(agg2, Wc, nullptr, AB, N);

    // BN0 stats via node-level algebra (no O(E) edge pass)
    bn0_node_kernel<<<512, 256, 0, stream>>>(AB, hist, odeg, rowptr, ssort, dS1, dS2, dX, N);
    bnprep0_kernel<<<1, 64, 0, stream>>>(dS1, dS2, dX, g_m0, be_m0, b_m0, s0, t0, E);

    // MLP1 (edge-tile GEMM, TE=256/512thr) -> z1 (sorted order), BN1 stats fused
    mlp1_fused_kernel<<<(E + 255) / 256, 512, 0, stream>>>(AB, ssort, dsort, b_m0,
                                                           s0, t0, W_m1, b_m1, z1, st1, E);
    bnprep1_kernel<<<1, 32, 0, stream>>>(st1, g_m1, be_m1, s1v, t1v, E);

    // MLP2 + sigmoid, scatter to original edge order
    mlp2_kernel<<<nbE, 256, 0, stream>>>(z1, esort, s1v, t1v, W_m2, b_m2, out, E);
}

// Round 9
// 694.816 us; speedup vs baseline: 1.1650x; 1.1650x over previous
//
#include <hip/hip_runtime.h>
#include <math.h>

static constexpr int IN_D = 256;
static constexpr int HIDD = 128;

// ---------------------------------------------------------------------------
// init: zero histograms and the f64 stat block (256 doubles)
__global__ void init_kernel(int* __restrict__ hist, int* __restrict__ odeg,
                            double* __restrict__ dsum, int n) {
    int i = blockIdx.x * 256 + threadIdx.x;
    if (i < n) { hist[i] = 0; odeg[i] = 0; }
    if (i < 256) dsum[i] = 0.0;
}

__global__ void hist_kernel(const int* __restrict__ src, const int* __restrict__ dst,
                            int* __restrict__ hist, int* __restrict__ odeg, int E) {
    int e = blockIdx.x * 256 + threadIdx.x;
    if (e < E) {
        atomicAdd(&hist[dst[e]], 1);
        atomicAdd(&odeg[src[e]], 1);
    }
}

// ---------------------------------------------------------------------------
// 3-phase parallel exclusive scan of hist[N] -> rowptr/cursor (+dinv)
// A: per-block sums (coalesced + LDS tree reduce)
__global__ __launch_bounds__(256)
void blocksum_kernel(const int* __restrict__ hist, int* __restrict__ bsum, int N) {
    __shared__ int red[256];
    const int t = threadIdx.x;
    int i = blockIdx.x * 256 + t;
    red[t] = (i < N) ? hist[i] : 0;
    __syncthreads();
#pragma unroll
    for (int off = 128; off > 0; off >>= 1) {
        if (t < off) red[t] += red[t + off];
        __syncthreads();
    }
    if (t == 0) bsum[blockIdx.x] = red[0];
}

// B: single-block exclusive scan of the <=256 block sums
__global__ __launch_bounds__(256)
void scanb_kernel(int* __restrict__ bsum, int NB) {
    __shared__ int s[256];
    const int t = threadIdx.x;
    int v = (t < NB) ? bsum[t] : 0;
    s[t] = v;
    __syncthreads();
#pragma unroll
    for (int off = 1; off < 256; off <<= 1) {
        int u = (t >= off) ? s[t - off] : 0;
        __syncthreads();
        s[t] += u;
        __syncthreads();
    }
    if (t < NB) bsum[t] = s[t] - v;  // exclusive prefix of block sums
}

// C: per-block exclusive scan + block offset; coalesced writes
__global__ __launch_bounds__(256)
void prefix_kernel(const int* __restrict__ hist, const int* __restrict__ bsum,
                   int* __restrict__ rowptr, int* __restrict__ cursor,
                   float* __restrict__ dinv, int N, int E) {
    __shared__ int s[256];
    const int t = threadIdx.x;
    int i = blockIdx.x * 256 + t;
    int v = (i < N) ? hist[i] : 0;
    s[t] = v;
    __syncthreads();
#pragma unroll
    for (int off = 1; off < 256; off <<= 1) {
        int u = (t >= off) ? s[t - off] : 0;
        __syncthreads();
        s[t] += u;
        __syncthreads();
    }
    if (i < N) {
        int run = bsum[blockIdx.x] + s[t] - v;  // exclusive prefix
        rowptr[i] = run;
        cursor[i] = run;
        dinv[i] = rsqrtf((float)v + 1.0f);      // +1 self-loop
    }
    if (blockIdx.x == 0 && t == 0) rowptr[N] = E;
}

__global__ void fill_kernel(const int* __restrict__ src, const int* __restrict__ dst,
                            int* __restrict__ cursor, int* __restrict__ ssort,
                            int* __restrict__ dsort, int* __restrict__ esort, int E) {
    int e = blockIdx.x * 256 + threadIdx.x;
    if (e < E) {
        int d = dst[e];
        int pos = atomicAdd(&cursor[d], 1);
        ssort[pos] = src[e];
        dsort[pos] = d;
        esort[pos] = e;
    }
}

// ---------------------------------------------------------------------------
// Generic tiled f32 GEMM: C[M,NCOL] = op(A[M,K]) @ W[K,NCOL] (+ bias)
template <int K, int NCOL, bool RELU, bool BIAS>
__global__ __launch_bounds__((NCOL / 4) * 16)
void mm_kernel(const float* __restrict__ A, const float* __restrict__ W,
               const float* __restrict__ bias, float* __restrict__ C, int M) {
    constexpr int MT = 64;
    constexpr int KK = 32;
    constexpr int TPB = (NCOL / 4) * (MT / 4);
    __shared__ float xs[KK][MT + 4];
    __shared__ float ws[KK][NCOL];

    const int t = threadIdx.x;
    const int m0 = blockIdx.x * MT;
    const int tc = t % (NCOL / 4);
    const int tr = t / (NCOL / 4);
    const int c0 = tc * 4, r0 = tr * 4;

    float acc[4][4] = {};

    for (int ko = 0; ko < K; ko += KK) {
        constexpr int NF4 = MT * KK / 4;
        for (int idx = t; idx < NF4; idx += TPB) {
            int m = idx >> 3;
            int jk = idx & 7;
            float4 v = make_float4(0.f, 0.f, 0.f, 0.f);
            if (m0 + m < M)
                v = *(const float4*)&A[(size_t)(m0 + m) * K + ko + jk * 4];
            if (RELU) {
                v.x = fmaxf(v.x, 0.f); v.y = fmaxf(v.y, 0.f);
                v.z = fmaxf(v.z, 0.f); v.w = fmaxf(v.w, 0.f);
            }
            xs[jk * 4 + 0][m] = v.x;
            xs[jk * 4 + 1][m] = v.y;
            xs[jk * 4 + 2][m] = v.z;
            xs[jk * 4 + 3][m] = v.w;
        }
        constexpr int WF4 = KK * NCOL / 4;
        const float4* Wp = (const float4*)(W + (size_t)ko * NCOL);
        float4* wsp = (float4*)&ws[0][0];
        for (int idx = t; idx < WF4; idx += TPB) wsp[idx] = Wp[idx];
        __syncthreads();

#pragma unroll
        for (int kk = 0; kk < KK; kk++) {
            float4 av = *(const float4*)&xs[kk][r0];
            float4 wv = *(const float4*)&ws[kk][c0];
            acc[0][0] += av.x * wv.x; acc[0][1] += av.x * wv.y;
            acc[0][2] += av.x * wv.z; acc[0][3] += av.x * wv.w;
            acc[1][0] += av.y * wv.x; acc[1][1] += av.y * wv.y;
            acc[1][2] += av.y * wv.z; acc[1][3] += av.y * wv.w;
            acc[2][0] += av.z * wv.x; acc[2][1] += av.z * wv.y;
            acc[2][2] += av.z * wv.z; acc[2][3] += av.z * wv.w;
            acc[3][0] += av.w * wv.x; acc[3][1] += av.w * wv.y;
            acc[3][2] += av.w * wv.z; acc[3][3] += av.w * wv.w;
        }
        __syncthreads();
    }

    float4 b4 = make_float4(0.f, 0.f, 0.f, 0.f);
    if (BIAS) b4 = *(const float4*)&bias[c0];
#pragma unroll
    for (int i = 0; i < 4; i++) {
        int row = m0 + r0 + i;
        if (row < M) {
            float4 o;
            o.x = acc[i][0] + b4.x; o.y = acc[i][1] + b4.y;
            o.z = acc[i][2] + b4.z; o.w = acc[i][3] + b4.w;
            *(float4*)&C[(size_t)row * NCOL + c0] = o;
        }
    }
}

// ---------------------------------------------------------------------------
// CSR gather aggregation: agg[n][c] = hW[n][c]*dinv[n]^2 + b[c]
//                                   + sum_{s in in(n)} hW[s][c]*dinv[s]*dinv[n]
template <int NC>
__global__ __launch_bounds__(256)
void agg_kernel(const float* __restrict__ hW, const float* __restrict__ dinv,
                const int* __restrict__ rowptr, const int* __restrict__ src_sorted,
                const float* __restrict__ b, float* __restrict__ agg, int N) {
    constexpr int TPN = NC / 4;
    constexpr int NPB = 256 / TPN;
    const int t = threadIdx.x;
    const int node = blockIdx.x * NPB + t / TPN;
    if (node >= N) return;
    const int c4 = (t % TPN) * 4;

    const float dn = dinv[node];
    float4 h = *(const float4*)&hW[(size_t)node * NC + c4];
    float4 bb = *(const float4*)&b[c4];
    float4 acc;
    acc.x = h.x * dn * dn + bb.x;
    acc.y = h.y * dn * dn + bb.y;
    acc.z = h.z * dn * dn + bb.z;
    acc.w = h.w * dn * dn + bb.w;

    const int i1 = rowptr[node + 1];
    for (int i = rowptr[node]; i < i1; i++) {
        int s = src_sorted[i];
        float w = dinv[s] * dn;
        float4 v = *(const float4*)&hW[(size_t)s * NC + c4];
        acc.x += v.x * w; acc.y += v.y * w; acc.z += v.z * w; acc.w += v.w * w;
    }
    *(float4*)&agg[(size_t)node * NC + c4] = acc;
}

// ---------------------------------------------------------------------------
// Build Wc[64][128] = [W_m0_top | W_m0_bot]
__global__ void concat_w_kernel(const float* __restrict__ Wm0, float* __restrict__ Wc) {
    int i = blockIdx.x * 256 + threadIdx.x;
    if (i < 64 * 128) {
        int k = i >> 7, j = i & 127;
        Wc[i] = (j < 64) ? Wm0[k * 64 + j] : Wm0[(64 + k) * 64 + (j - 64)];
    }
}

// ---------------------------------------------------------------------------
// BN0 stats via node-level algebra (replaces the O(E) z0stats pass).
__global__ __launch_bounds__(256)
void bn0_node_kernel(const float* __restrict__ AB, const int* __restrict__ ideg,
                     const int* __restrict__ odeg, const int* __restrict__ rowptr,
                     const int* __restrict__ ssort,
                     double* __restrict__ dS1, double* __restrict__ dS2,
                     double* __restrict__ dX, int N) {
    const int t = threadIdx.x;
    const int c4 = (t & 15) * 4;
    const int slot = t >> 4;  // 16 node-slots per block
    float rS1[4] = {}, rS2[4] = {}, rX[4] = {};

    for (int n = blockIdx.x * 16 + slot; n < N; n += gridDim.x * 16) {
        float od = (float)odeg[n];
        float id = (float)ideg[n];
        float4 A4 = *(const float4*)&AB[(size_t)n * 128 + c4];
        float4 B4 = *(const float4*)&AB[(size_t)n * 128 + 64 + c4];
        float4 ca = make_float4(0.f, 0.f, 0.f, 0.f);
        const int i1 = rowptr[n + 1];
        for (int i = rowptr[n]; i < i1; i++) {
            int s = ssort[i];
            float4 v = *(const float4*)&AB[(size_t)s * 128 + c4];
            ca.x += v.x; ca.y += v.y; ca.z += v.z; ca.w += v.w;
        }
        rS1[0] += od * A4.x + id * B4.x;
        rS1[1] += od * A4.y + id * B4.y;
        rS1[2] += od * A4.z + id * B4.z;
        rS1[3] += od * A4.w + id * B4.w;
        rS2[0] += od * A4.x * A4.x + id * B4.x * B4.x;
        rS2[1] += od * A4.y * A4.y + id * B4.y * B4.y;
        rS2[2] += od * A4.z * A4.z + id * B4.z * B4.z;
        rS2[3] += od * A4.w * A4.w + id * B4.w * B4.w;
        rX[0] += ca.x * B4.x; rX[1] += ca.y * B4.y;
        rX[2] += ca.z * B4.z; rX[3] += ca.w * B4.w;
    }

    __shared__ float m1[16][64], m2[16][64], mx[16][64];
#pragma unroll
    for (int i = 0; i < 4; i++) {
        m1[slot][c4 + i] = rS1[i];
        m2[slot][c4 + i] = rS2[i];
        mx[slot][c4 + i] = rX[i];
    }
    __syncthreads();
    if (t < 64) {
        float a1 = 0.f, a2 = 0.f, ax = 0.f;
#pragma unroll
        for (int q = 0; q < 16; q++) { a1 += m1[q][t]; a2 += m2[q][t]; ax += mx[q][t]; }
        atomicAdd(&dS1[t], (double)a1);
        atomicAdd(&dS2[t], (double)a2);
        atomicAdd(&dX[t], (double)ax);
    }
}

// mean = S1/E + bm ; var = (S2 + 2X)/E - (S1/E)^2  (bm terms cancel in var)
__global__ void bnprep0_kernel(const double* __restrict__ dS1, const double* __restrict__ dS2,
                               const double* __restrict__ dX,
                               const float* __restrict__ g, const float* __restrict__ be,
                               const float* __restrict__ bm,
                               float* __restrict__ s0, float* __restrict__ t0, int E) {
    int c = threadIdx.x;
    if (c < 64) {
        double a1 = dS1[c] / (double)E;
        double var = (dS2[c] + 2.0 * dX[c]) / (double)E - a1 * a1;
        double mean = a1 + (double)bm[c];
        double inv = 1.0 / sqrt(var + 1e-5);
        float s = (float)((double)g[c] * inv);
        float t = (float)((double)be[c] - (double)s * mean);
        s0[c] = s; t0[c] = t;
    }
}

// ---------------------------------------------------------------------------
// MLP layer 1 as an edge-tile GEMM (TE=256, 512 threads), BN1 stats fused.
__global__ __launch_bounds__(512)
void mlp1_fused_kernel(const float* __restrict__ AB, const int* __restrict__ ssort,
                       const int* __restrict__ dsort, const float* __restrict__ bm0v,
                       const float* __restrict__ s0v, const float* __restrict__ t0v,
                       const float* __restrict__ Wm1, const float* __restrict__ bm1,
                       float* __restrict__ z1, double* __restrict__ st, int E) {
    constexpr int TE = 256;
    __shared__ float smem[64 * TE];      // yt[k][e], later ls1/ls2
    __shared__ float wls[64 * 32];
    __shared__ float svls[64], tvls[64], bmls[64], b1ls[32];

    const int t = threadIdx.x;
    for (int i = t; i < 2048; i += 512) wls[i] = Wm1[i];
    if (t < 64) { svls[t] = s0v[t]; tvls[t] = t0v[t]; bmls[t] = bm0v[t]; }
    if (t < 32) b1ls[t] = bm1[t];
    __syncthreads();

    // ---- stage: 2 threads per edge, each covers 32 channels ----
    const int base = blockIdx.x * TE;
    const int le = t >> 1, half = t & 1;
    const int pos = base + le;
    if (pos < E) {
        const int s = ssort[pos], d = dsort[pos];
        const float* Ar = AB + (size_t)s * 128;
        const float* Br = AB + (size_t)d * 128 + 64;
#pragma unroll
        for (int q = 0; q < 8; q++) {
            int c = half * 32 + q * 4;
            float4 a = *(const float4*)&Ar[c];
            float4 b = *(const float4*)&Br[c];
            float4 sv = *(const float4*)&svls[c];
            float4 tv = *(const float4*)&tvls[c];
            float4 mv = *(const float4*)&bmls[c];
            smem[(c + 0) * TE + le] = fmaxf(sv.x * (a.x + b.x + mv.x) + tv.x, 0.f);
            smem[(c + 1) * TE + le] = fmaxf(sv.y * (a.y + b.y + mv.y) + tv.y, 0.f);
            smem[(c + 2) * TE + le] = fmaxf(sv.z * (a.z + b.z + mv.z) + tv.z, 0.f);
            smem[(c + 3) * TE + le] = fmaxf(sv.w * (a.w + b.w + mv.w) + tv.w, 0.f);
        }
    } else {
#pragma unroll
        for (int q = 0; q < 8; q++) {
            int c = half * 32 + q * 4;
            smem[(c + 0) * TE + le] = 0.f; smem[(c + 1) * TE + le] = 0.f;
            smem[(c + 2) * TE + le] = 0.f; smem[(c + 3) * TE + le] = 0.f;
        }
    }
    __syncthreads();

    // ---- GEMM: out tile 256 edges x 32 cols, 4x4 per thread ----
    const int tr = t >> 3, tc = t & 7;   // tr 0..63, tc 0..7
    const int r0 = tr * 4, c0 = tc * 4;
    float acc[4][4];
#pragma unroll
    for (int i = 0; i < 4; i++) {
        acc[i][0] = b1ls[c0 + 0]; acc[i][1] = b1ls[c0 + 1];
        acc[i][2] = b1ls[c0 + 2]; acc[i][3] = b1ls[c0 + 3];
    }
#pragma unroll 8
    for (int kk = 0; kk < 64; kk++) {
        float4 av = *(const float4*)&smem[kk * TE + r0];
        float4 wv = *(const float4*)&wls[kk * 32 + c0];
        acc[0][0] += av.x * wv.x; acc[0][1] += av.x * wv.y;
        acc[0][2] += av.x * wv.z; acc[0][3] += av.x * wv.w;
        acc[1][0] += av.y * wv.x; acc[1][1] += av.y * wv.y;
        acc[1][2] += av.y * wv.z; acc[1][3] += av.y * wv.w;
        acc[2][0] += av.z * wv.x; acc[2][1] += av.z * wv.y;
        acc[2][2] += av.z * wv.z; acc[2][3] += av.z * wv.w;
        acc[3][0] += av.w * wv.x; acc[3][1] += av.w * wv.y;
        acc[3][2] += av.w * wv.z; acc[3][3] += av.w * wv.w;
    }

    // ---- z1 write + local BN1 stats ----
    float cs1[4] = {0.f, 0.f, 0.f, 0.f};
    float cs2[4] = {0.f, 0.f, 0.f, 0.f};
#pragma unroll
    for (int i = 0; i < 4; i++) {
        int pz = base + r0 + i;
        if (pz < E) {
            float4 o;
            o.x = acc[i][0]; o.y = acc[i][1]; o.z = acc[i][2]; o.w = acc[i][3];
            *(float4*)&z1[(size_t)pz * 32 + c0] = o;
            cs1[0] += o.x; cs1[1] += o.y; cs1[2] += o.z; cs1[3] += o.w;
            cs2[0] += o.x * o.x; cs2[1] += o.y * o.y;
            cs2[2] += o.z * o.z; cs2[3] += o.w * o.w;
        }
    }
    __syncthreads();                 // yt dead -> overlay stats
    float* ls1 = smem;
    float* ls2 = smem + 64 * 32;
    ls1[tr * 32 + c0 + 0] = cs1[0]; ls1[tr * 32 + c0 + 1] = cs1[1];
    ls1[tr * 32 + c0 + 2] = cs1[2]; ls1[tr * 32 + c0 + 3] = cs1[3];
    ls2[tr * 32 + c0 + 0] = cs2[0]; ls2[tr * 32 + c0 + 1] = cs2[1];
    ls2[tr * 32 + c0 + 2] = cs2[2]; ls2[tr * 32 + c0 + 3] = cs2[3];
    __syncthreads();
    if (t < 32) {
        float a1 = 0.f, a2 = 0.f;
#pragma unroll
        for (int r = 0; r < 64; r++) { a1 += ls1[r * 32 + t]; a2 += ls2[r * 32 + t]; }
        atomicAdd(&st[t], (double)a1);
        atomicAdd(&st[32 + t], (double)a2);
    }
}

__global__ void bnprep1_kernel(const double* __restrict__ st,
                               const float* __restrict__ g, const float* __restrict__ be,
                               float* __restrict__ s1, float* __restrict__ t1, int E) {
    int c = threadIdx.x;
    if (c < 32) {
        double mu = st[c] / (double)E;
        double var = st[32 + c] / (double)E - mu * mu;
        double inv = 1.0 / sqrt(var + 1e-5);
        float s = (float)((double)g[c] * inv);
        float t = (float)((double)be[c] - (double)s * mu);
        s1[c] = s; t1[c] = t;
    }
}

// MLP layer 2 + sigmoid; z1 is in sorted order -> scatter out via esort
__global__ void mlp2_kernel(const float* __restrict__ z1, const int* __restrict__ esort,
                            const float* __restrict__ s1, const float* __restrict__ t1,
                            const float* __restrict__ Wm2, const float* __restrict__ bm2,
                            float* __restrict__ out, int E) {
    int pos = blockIdx.x * 256 + threadIdx.x;
    if (pos >= E) return;
    const float* zr = z1 + (size_t)pos * 32;
    float acc = bm2[0];
#pragma unroll
    for (int k = 0; k < 32; k += 4) {
        float4 z4 = *(const float4*)&zr[k];
        float4 sv = *(const float4*)&s1[k];
        float4 tv = *(const float4*)&t1[k];
        float4 wv = *(const float4*)&Wm2[k];
        acc += fmaxf(sv.x * z4.x + tv.x, 0.f) * wv.x;
        acc += fmaxf(sv.y * z4.y + tv.y, 0.f) * wv.y;
        acc += fmaxf(sv.z * z4.z + tv.z, 0.f) * wv.z;
        acc += fmaxf(sv.w * z4.w + tv.w, 0.f) * wv.w;
    }
    out[esort[pos]] = 1.f / (1.f + expf(-acc));
}

// ---------------------------------------------------------------------------
extern "C" void kernel_launch(void* const* d_in, const int* in_sizes, int n_in,
                              void* d_out, int out_size, void* d_ws, size_t ws_size,
                              hipStream_t stream) {
    const float* x      = (const float*)d_in[0];
    const int*   eidx   = (const int*)d_in[1];
    const float* W_emb  = (const float*)d_in[2];
    const float* b_emb  = (const float*)d_in[3];
    const float* W_g1   = (const float*)d_in[4];
    const float* b_g1   = (const float*)d_in[5];
    const float* W_g2   = (const float*)d_in[6];
    const float* b_g2   = (const float*)d_in[7];
    const float* W_m0   = (const float*)d_in[8];
    const float* b_m0   = (const float*)d_in[9];
    const float* g_m0   = (const float*)d_in[10];
    const float* be_m0  = (const float*)d_in[11];
    const float* W_m1   = (const float*)d_in[12];
    const float* b_m1   = (const float*)d_in[13];
    const float* g_m1   = (const float*)d_in[14];
    const float* be_m1  = (const float*)d_in[15];
    const float* W_m2   = (const float*)d_in[16];
    const float* b_m2   = (const float*)d_in[17];
    float* out = (float*)d_out;

    const int N = in_sizes[0] / IN_D;   // 50000
    const int E = in_sizes[1] / 2;      // 800000
    const int* src = eidx;
    const int* dst = eidx + E;

    char* p = (char*)d_ws;
    auto alloc = [&](size_t bytes) {
        void* r = (void*)p;
        p += (bytes + 255) & ~(size_t)255;
        return r;
    };
    int*    hist   = (int*)alloc((size_t)N * 4);            // in-degree (raw)
    int*    odeg   = (int*)alloc((size_t)N * 4);            // out-degree (raw)
    int*    rowptr = (int*)alloc((size_t)(N + 1) * 4);
    int*    cursor = (int*)alloc((size_t)N * 4);
    int*    bsum   = (int*)alloc(256 * 4);                  // block sums for scan
    int*    ssort  = (int*)alloc((size_t)E * 4);
    int*    dsort  = (int*)alloc((size_t)E * 4);
    int*    esort  = (int*)alloc((size_t)E * 4);
    float*  dinv   = (float*)alloc((size_t)N * 4);
    float*  B2     = (float*)alloc((size_t)N * HIDD * 4);   // h0, later agg2
    float*  B3     = (float*)alloc((size_t)N * HIDD * 4);   // hW1, later hW2
    float*  B4     = (float*)alloc((size_t)N * HIDD * 4);   // agg1, later AB
    float*  z1     = (float*)alloc((size_t)E * 32 * 4);
    float*  Wc     = (float*)alloc(64 * 128 * 4);
    double* dsum   = (double*)alloc(256 * 8);               // S1|S2|X|st1
    float*  s0     = (float*)alloc(64 * 4);
    float*  t0     = (float*)alloc(64 * 4);
    float*  s1v    = (float*)alloc(32 * 4);
    float*  t1v    = (float*)alloc(32 * 4);

    double* dS1 = dsum;
    double* dS2 = dsum + 64;
    double* dX  = dsum + 128;
    double* st1 = dsum + 192;

    float* h0   = B2;  float* agg2 = B2;
    float* hW1  = B3;  float* hW2  = B3;
    float* agg1 = B4;  float* AB   = B4;

    const int nbE = (E + 255) / 256;
    const int nbN = (N + 255) / 256;   // 196

    // CSR build (dst-sorted) + degrees + dinv — parallel 3-phase scan
    init_kernel<<<nbN, 256, 0, stream>>>(hist, odeg, dsum, N);
    hist_kernel<<<nbE, 256, 0, stream>>>(src, dst, hist, odeg, E);
    blocksum_kernel<<<nbN, 256, 0, stream>>>(hist, bsum, N);
    scanb_kernel<<<1, 256, 0, stream>>>(bsum, nbN);
    prefix_kernel<<<nbN, 256, 0, stream>>>(hist, bsum, rowptr, cursor, dinv, N, E);
    fill_kernel<<<nbE, 256, 0, stream>>>(src, dst, cursor, ssort, dsort, esort, E);

    // embedding: h0 = x @ W_emb + b_emb
    mm_kernel<256, 128, false, true><<<(N + 63) / 64, 512, 0, stream>>>(x, W_emb, b_emb, h0, N);

    // GCN1
    mm_kernel<128, 128, false, false><<<(N + 63) / 64, 512, 0, stream>>>(h0, W_g1, nullptr, hW1, N);
    agg_kernel<128><<<(N + 7) / 8, 256, 0, stream>>>(hW1, dinv, rowptr, ssort, b_g1, agg1, N);

    // GCN2 (relu on agg1 fused into GEMM staging)
    mm_kernel<128, 64, true, false><<<(N + 63) / 64, 256, 0, stream>>>(agg1, W_g2, nullptr, hW2, N);
    agg_kernel<64><<<(N + 15) / 16, 256, 0, stream>>>(hW2, dinv, rowptr, ssort, b_g2, agg2, N);

    // AB = h2 @ [Wtop|Wbot]  (edge MLP layer-0 factorization)
    concat_w_kernel<<<32, 256, 0, stream>>>(W_m0, Wc);
    mm_kernel<64, 128, false, false><<<(N + 63) / 64, 512, 0, stream>>>(agg2, Wc, nullptr, AB, N);

    // BN0 stats via node-level algebra (no O(E) edge pass)
    bn0_node_kernel<<<512, 256, 0, stream>>>(AB, hist, odeg, rowptr, ssort, dS1, dS2, dX, N);
    bnprep0_kernel<<<1, 64, 0, stream>>>(dS1, dS2, dX, g_m0, be_m0, b_m0, s0, t0, E);

    // MLP1 (edge-tile GEMM, TE=256/512thr) -> z1 (sorted order), BN1 stats fused
    mlp1_fused_kernel<<<(E + 255) / 256, 512, 0, stream>>>(AB, ssort, dsort, b_m0,
                                                           s0, t0, W_m1, b_m1, z1, st1, E);
    bnprep1_kernel<<<1, 32, 0, stream>>>(st1, g_m1, be_m1, s1v, t1v, E);

    // MLP2 + sigmoid, scatter to original edge order
    mlp2_kernel<<<nbE, 256, 0, stream>>>(z1, esort, s1v, t1v, W_m2, b_m2, out, E);
}

// Round 11
// 620.749 us; speedup vs baseline: 1.3040x; 1.1193x over previous
//
#include <hip/hip_runtime.h>
#include <math.h>

static constexpr int IN_D = 256;
static constexpr int HIDD = 128;

// ---------------------------------------------------------------------------
__global__ void init_kernel(int* __restrict__ hist, int* __restrict__ odeg,
                            double* __restrict__ dsum, int n) {
    int i = blockIdx.x * 256 + threadIdx.x;
    if (i < n) { hist[i] = 0; odeg[i] = 0; }
    if (i < 256) dsum[i] = 0.0;
}

__global__ void hist_kernel(const int* __restrict__ src, const int* __restrict__ dst,
                            int* __restrict__ hist, int* __restrict__ odeg, int E) {
    int e = blockIdx.x * 256 + threadIdx.x;
    if (e < E) {
        atomicAdd(&hist[dst[e]], 1);
        atomicAdd(&odeg[src[e]], 1);
    }
}

// ---------------------------------------------------------------------------
// 3-phase parallel exclusive scan of hist[N] -> rowptr/cursor (+dinv)
__global__ __launch_bounds__(256)
void blocksum_kernel(const int* __restrict__ hist, int* __restrict__ bsum, int N) {
    __shared__ int red[256];
    const int t = threadIdx.x;
    int i = blockIdx.x * 256 + t;
    red[t] = (i < N) ? hist[i] : 0;
    __syncthreads();
#pragma unroll
    for (int off = 128; off > 0; off >>= 1) {
        if (t < off) red[t] += red[t + off];
        __syncthreads();
    }
    if (t == 0) bsum[blockIdx.x] = red[0];
}

__global__ __launch_bounds__(256)
void scanb_kernel(int* __restrict__ bsum, int NB) {
    __shared__ int s[256];
    const int t = threadIdx.x;
    int v = (t < NB) ? bsum[t] : 0;
    s[t] = v;
    __syncthreads();
#pragma unroll
    for (int off = 1; off < 256; off <<= 1) {
        int u = (t >= off) ? s[t - off] : 0;
        __syncthreads();
        s[t] += u;
        __syncthreads();
    }
    if (t < NB) bsum[t] = s[t] - v;  // exclusive prefix of block sums
}

__global__ __launch_bounds__(256)
void prefix_kernel(const int* __restrict__ hist, const int* __restrict__ bsum,
                   int* __restrict__ rowptr, int* __restrict__ cursor,
                   float* __restrict__ dinv, int N, int E) {
    __shared__ int s[256];
    const int t = threadIdx.x;
    int i = blockIdx.x * 256 + t;
    int v = (i < N) ? hist[i] : 0;
    s[t] = v;
    __syncthreads();
#pragma unroll
    for (int off = 1; off < 256; off <<= 1) {
        int u = (t >= off) ? s[t - off] : 0;
        __syncthreads();
        s[t] += u;
        __syncthreads();
    }
    if (i < N) {
        int run = bsum[blockIdx.x] + s[t] - v;  // exclusive prefix
        rowptr[i] = run;
        cursor[i] = run;
        dinv[i] = rsqrtf((float)v + 1.0f);      // +1 self-loop
    }
    if (blockIdx.x == 0 && t == 0) rowptr[N] = E;
}

__global__ void fill_kernel(const int* __restrict__ src, const int* __restrict__ dst,
                            int* __restrict__ cursor, int* __restrict__ ssort,
                            int* __restrict__ dsort, int* __restrict__ esort, int E) {
    int e = blockIdx.x * 256 + threadIdx.x;
    if (e < E) {
        int d = dst[e];
        int pos = atomicAdd(&cursor[d], 1);
        ssort[pos] = src[e];
        dsort[pos] = d;
        esort[pos] = e;
    }
}

// ---------------------------------------------------------------------------
// Generic tiled f32 GEMM: C[M,NCOL] = op(A[M,K]) @ W[K,NCOL] (+ bias)
template <int K, int NCOL, bool RELU, bool BIAS>
__global__ __launch_bounds__((NCOL / 4) * 16)
void mm_kernel(const float* __restrict__ A, const float* __restrict__ W,
               const float* __restrict__ bias, float* __restrict__ C, int M) {
    constexpr int MT = 64;
    constexpr int KK = 32;
    constexpr int TPB = (NCOL / 4) * (MT / 4);
    __shared__ float xs[KK][MT + 4];
    __shared__ float ws[KK][NCOL];

    const int t = threadIdx.x;
    const int m0 = blockIdx.x * MT;
    const int tc = t % (NCOL / 4);
    const int tr = t / (NCOL / 4);
    const int c0 = tc * 4, r0 = tr * 4;

    float acc[4][4] = {};

    for (int ko = 0; ko < K; ko += KK) {
        constexpr int NF4 = MT * KK / 4;
        for (int idx = t; idx < NF4; idx += TPB) {
            int m = idx >> 3;
            int jk = idx & 7;
            float4 v = make_float4(0.f, 0.f, 0.f, 0.f);
            if (m0 + m < M)
                v = *(const float4*)&A[(size_t)(m0 + m) * K + ko + jk * 4];
            if (RELU) {
                v.x = fmaxf(v.x, 0.f); v.y = fmaxf(v.y, 0.f);
                v.z = fmaxf(v.z, 0.f); v.w = fmaxf(v.w, 0.f);
            }
            xs[jk * 4 + 0][m] = v.x;
            xs[jk * 4 + 1][m] = v.y;
            xs[jk * 4 + 2][m] = v.z;
            xs[jk * 4 + 3][m] = v.w;
        }
        constexpr int WF4 = KK * NCOL / 4;
        const float4* Wp = (const float4*)(W + (size_t)ko * NCOL);
        float4* wsp = (float4*)&ws[0][0];
        for (int idx = t; idx < WF4; idx += TPB) wsp[idx] = Wp[idx];
        __syncthreads();

#pragma unroll
        for (int kk = 0; kk < KK; kk++) {
            float4 av = *(const float4*)&xs[kk][r0];
            float4 wv = *(const float4*)&ws[kk][c0];
            acc[0][0] += av.x * wv.x; acc[0][1] += av.x * wv.y;
            acc[0][2] += av.x * wv.z; acc[0][3] += av.x * wv.w;
            acc[1][0] += av.y * wv.x; acc[1][1] += av.y * wv.y;
            acc[1][2] += av.y * wv.z; acc[1][3] += av.y * wv.w;
            acc[2][0] += av.z * wv.x; acc[2][1] += av.z * wv.y;
            acc[2][2] += av.z * wv.z; acc[2][3] += av.z * wv.w;
            acc[3][0] += av.w * wv.x; acc[3][1] += av.w * wv.y;
            acc[3][2] += av.w * wv.z; acc[3][3] += av.w * wv.w;
        }
        __syncthreads();
    }

    float4 b4 = make_float4(0.f, 0.f, 0.f, 0.f);
    if (BIAS) b4 = *(const float4*)&bias[c0];
#pragma unroll
    for (int i = 0; i < 4; i++) {
        int row = m0 + r0 + i;
        if (row < M) {
            float4 o;
            o.x = acc[i][0] + b4.x; o.y = acc[i][1] + b4.y;
            o.z = acc[i][2] + b4.z; o.w = acc[i][3] + b4.w;
            *(float4*)&C[(size_t)row * NCOL + c0] = o;
        }
    }
}

// ---------------------------------------------------------------------------
// CSR gather aggregation, 2-way unrolled for gather ILP.
template <int NC>
__global__ __launch_bounds__(256)
void agg_kernel(const float* __restrict__ hW, const float* __restrict__ dinv,
                const int* __restrict__ rowptr, const int* __restrict__ src_sorted,
                const float* __restrict__ b, float* __restrict__ agg, int N) {
    constexpr int TPN = NC / 4;
    constexpr int NPB = 256 / TPN;
    const int t = threadIdx.x;
    const int node = blockIdx.x * NPB + t / TPN;
    if (node >= N) return;
    const int c4 = (t % TPN) * 4;

    const float dn = dinv[node];
    float4 h = *(const float4*)&hW[(size_t)node * NC + c4];
    float4 bb = *(const float4*)&b[c4];
    float4 acc;
    acc.x = h.x * dn * dn + bb.x;
    acc.y = h.y * dn * dn + bb.y;
    acc.z = h.z * dn * dn + bb.z;
    acc.w = h.w * dn * dn + bb.w;

    int i = rowptr[node];
    const int i1 = rowptr[node + 1];
    for (; i + 2 <= i1; i += 2) {
        int sa = src_sorted[i];
        int sb = src_sorted[i + 1];
        float wa = dinv[sa] * dn;
        float wb = dinv[sb] * dn;
        float4 va = *(const float4*)&hW[(size_t)sa * NC + c4];
        float4 vb = *(const float4*)&hW[(size_t)sb * NC + c4];
        acc.x += va.x * wa + vb.x * wb;
        acc.y += va.y * wa + vb.y * wb;
        acc.z += va.z * wa + vb.z * wb;
        acc.w += va.w * wa + vb.w * wb;
    }
    if (i < i1) {
        int s = src_sorted[i];
        float w = dinv[s] * dn;
        float4 v = *(const float4*)&hW[(size_t)s * NC + c4];
        acc.x += v.x * w; acc.y += v.y * w; acc.z += v.z * w; acc.w += v.w * w;
    }
    *(float4*)&agg[(size_t)node * NC + c4] = acc;
}

// ---------------------------------------------------------------------------
// Build Wc[64][128] = [W_m0_top | W_m0_bot]
__global__ void concat_w_kernel(const float* __restrict__ Wm0, float* __restrict__ Wc) {
    int i = blockIdx.x * 256 + threadIdx.x;
    if (i < 64 * 128) {
        int k = i >> 7, j = i & 127;
        Wc[i] = (j < 64) ? Wm0[k * 64 + j] : Wm0[(64 + k) * 64 + (j - 64)];
    }
}

// ---------------------------------------------------------------------------
// BN0 stats via node-level algebra (2-way unrolled CSR gather).
__global__ __launch_bounds__(256)
void bn0_node_kernel(const float* __restrict__ AB, const int* __restrict__ ideg,
                     const int* __restrict__ odeg, const int* __restrict__ rowptr,
                     const int* __restrict__ ssort,
                     double* __restrict__ dS1, double* __restrict__ dS2,
                     double* __restrict__ dX, int N) {
    const int t = threadIdx.x;
    const int c4 = (t & 15) * 4;
    const int slot = t >> 4;  // 16 node-slots per block
    float rS1[4] = {}, rS2[4] = {}, rX[4] = {};

    for (int n = blockIdx.x * 16 + slot; n < N; n += gridDim.x * 16) {
        float od = (float)odeg[n];
        float id = (float)ideg[n];
        float4 A4 = *(const float4*)&AB[(size_t)n * 128 + c4];
        float4 B4 = *(const float4*)&AB[(size_t)n * 128 + 64 + c4];
        float4 ca = make_float4(0.f, 0.f, 0.f, 0.f);
        int i = rowptr[n];
        const int i1 = rowptr[n + 1];
        for (; i + 2 <= i1; i += 2) {
            int sa = ssort[i], sb = ssort[i + 1];
            float4 va = *(const float4*)&AB[(size_t)sa * 128 + c4];
            float4 vb = *(const float4*)&AB[(size_t)sb * 128 + c4];
            ca.x += va.x + vb.x; ca.y += va.y + vb.y;
            ca.z += va.z + vb.z; ca.w += va.w + vb.w;
        }
        if (i < i1) {
            int s = ssort[i];
            float4 v = *(const float4*)&AB[(size_t)s * 128 + c4];
            ca.x += v.x; ca.y += v.y; ca.z += v.z; ca.w += v.w;
        }
        rS1[0] += od * A4.x + id * B4.x;
        rS1[1] += od * A4.y + id * B4.y;
        rS1[2] += od * A4.z + id * B4.z;
        rS1[3] += od * A4.w + id * B4.w;
        rS2[0] += od * A4.x * A4.x + id * B4.x * B4.x;
        rS2[1] += od * A4.y * A4.y + id * B4.y * B4.y;
        rS2[2] += od * A4.z * A4.z + id * B4.z * B4.z;
        rS2[3] += od * A4.w * A4.w + id * B4.w * B4.w;
        rX[0] += ca.x * B4.x; rX[1] += ca.y * B4.y;
        rX[2] += ca.z * B4.z; rX[3] += ca.w * B4.w;
    }

    __shared__ float m1[16][64], m2[16][64], mx[16][64];
#pragma unroll
    for (int i = 0; i < 4; i++) {
        m1[slot][c4 + i] = rS1[i];
        m2[slot][c4 + i] = rS2[i];
        mx[slot][c4 + i] = rX[i];
    }
    __syncthreads();
    if (t < 64) {
        float a1 = 0.f, a2 = 0.f, ax = 0.f;
#pragma unroll
        for (int q = 0; q < 16; q++) { a1 += m1[q][t]; a2 += m2[q][t]; ax += mx[q][t]; }
        atomicAdd(&dS1[t], (double)a1);
        atomicAdd(&dS2[t], (double)a2);
        atomicAdd(&dX[t], (double)ax);
    }
}

// mean = S1/E + bm ; var = (S2 + 2X)/E - (S1/E)^2  (bm terms cancel in var)
__global__ void bnprep0_kernel(const double* __restrict__ dS1, const double* __restrict__ dS2,
                               const double* __restrict__ dX,
                               const float* __restrict__ g, const float* __restrict__ be,
                               const float* __restrict__ bm,
                               float* __restrict__ s0, float* __restrict__ t0, int E) {
    int c = threadIdx.x;
    if (c < 64) {
        double a1 = dS1[c] / (double)E;
        double var = (dS2[c] + 2.0 * dX[c]) / (double)E - a1 * a1;
        double mean = a1 + (double)bm[c];
        double inv = 1.0 / sqrt(var + 1e-5);
        float s = (float)((double)g[c] * inv);
        float t = (float)((double)be[c] - (double)s * mean);
        s0[c] = s; t0[c] = t;
    }
}

// ---------------------------------------------------------------------------
// MLP layer 1 as an edge-tile GEMM (TE=256, 512 threads), split-K staging:
// yt holds only 32 k at a time (32KB) -> ~41KB LDS -> 3 blocks/CU.
__global__ __launch_bounds__(512)
void mlp1_fused_kernel(const float* __restrict__ AB, const int* __restrict__ ssort,
                       const int* __restrict__ dsort, const float* __restrict__ bm0v,
                       const float* __restrict__ s0v, const float* __restrict__ t0v,
                       const float* __restrict__ Wm1, const float* __restrict__ bm1,
                       float* __restrict__ z1, double* __restrict__ st, int E) {
    constexpr int TE = 256;
    __shared__ float yt[32 * TE];        // one K-half of y0^T; later stats overlay
    __shared__ float wls[64 * 32];
    __shared__ float svls[64], tvls[64], bmls[64], b1ls[32];

    const int t = threadIdx.x;
    for (int i = t; i < 2048; i += 512) wls[i] = Wm1[i];
    if (t < 64) { svls[t] = s0v[t]; tvls[t] = t0v[t]; bmls[t] = bm0v[t]; }
    if (t < 32) b1ls[t] = bm1[t];
    __syncthreads();

    const int base = blockIdx.x * TE;
    const int le = t >> 1, half = t & 1;   // 2 threads/edge; half picks 16 channels/phase
    const int pos = base + le;
    const bool valid = pos < E;
    const int s = valid ? ssort[pos] : 0;
    const int d = valid ? dsort[pos] : 0;
    const float* Ar = AB + (size_t)s * 128;
    const float* Br = AB + (size_t)d * 128 + 64;

    const int tr = t >> 3, tc = t & 7;     // tr 0..63 edge groups, tc 0..7 col groups
    const int r0 = tr * 4, c0 = tc * 4;
    float acc[4][4] = {};

#pragma unroll
    for (int ph = 0; ph < 2; ph++) {
        if (ph) __syncthreads();           // prior GEMM reads done before overwrite
        const int cb = ph * 32 + half * 16;
        if (valid) {
#pragma unroll
            for (int q = 0; q < 4; q++) {
                int c = cb + q * 4;
                int kl = c - ph * 32;      // local k 0..31
                float4 a = *(const float4*)&Ar[c];
                float4 b = *(const float4*)&Br[c];
                float4 sv = *(const float4*)&svls[c];
                float4 tv = *(const float4*)&tvls[c];
                float4 mv = *(const float4*)&bmls[c];
                yt[(kl + 0) * TE + le] = fmaxf(sv.x * (a.x + b.x + mv.x) + tv.x, 0.f);
                yt[(kl + 1) * TE + le] = fmaxf(sv.y * (a.y + b.y + mv.y) + tv.y, 0.f);
                yt[(kl + 2) * TE + le] = fmaxf(sv.z * (a.z + b.z + mv.z) + tv.z, 0.f);
                yt[(kl + 3) * TE + le] = fmaxf(sv.w * (a.w + b.w + mv.w) + tv.w, 0.f);
            }
        } else {
#pragma unroll
            for (int q = 0; q < 4; q++) {
                int kl = half * 16 + q * 4;
                yt[(kl + 0) * TE + le] = 0.f; yt[(kl + 1) * TE + le] = 0.f;
                yt[(kl + 2) * TE + le] = 0.f; yt[(kl + 3) * TE + le] = 0.f;
            }
        }
        __syncthreads();

#pragma unroll 8
        for (int kk = 0; kk < 32; kk++) {
            float4 av = *(const float4*)&yt[kk * TE + r0];
            float4 wv = *(const float4*)&wls[(ph * 32 + kk) * 32 + c0];
            acc[0][0] += av.x * wv.x; acc[0][1] += av.x * wv.y;
            acc[0][2] += av.x * wv.z; acc[0][3] += av.x * wv.w;
            acc[1][0] += av.y * wv.x; acc[1][1] += av.y * wv.y;
            acc[1][2] += av.y * wv.z; acc[1][3] += av.y * wv.w;
            acc[2][0] += av.z * wv.x; acc[2][1] += av.z * wv.y;
            acc[2][2] += av.z * wv.z; acc[2][3] += av.z * wv.w;
            acc[3][0] += av.w * wv.x; acc[3][1] += av.w * wv.y;
            acc[3][2] += av.w * wv.z; acc[3][3] += av.w * wv.w;
        }
    }

    // ---- z1 write (+bias) + local BN1 stats ----
    float cs1[4] = {0.f, 0.f, 0.f, 0.f};
    float cs2[4] = {0.f, 0.f, 0.f, 0.f};
    float4 bo = *(const float4*)&b1ls[c0];
#pragma unroll
    for (int i = 0; i < 4; i++) {
        int pz = base + r0 + i;
        if (pz < E) {
            float4 o;
            o.x = acc[i][0] + bo.x; o.y = acc[i][1] + bo.y;
            o.z = acc[i][2] + bo.z; o.w = acc[i][3] + bo.w;
            *(float4*)&z1[(size_t)pz * 32 + c0] = o;
            cs1[0] += o.x; cs1[1] += o.y; cs1[2] += o.z; cs1[3] += o.w;
            cs2[0] += o.x * o.x; cs2[1] += o.y * o.y;
            cs2[2] += o.z * o.z; cs2[3] += o.w * o.w;
        }
    }
    __syncthreads();                 // yt dead -> overlay stats
    float* ls1 = yt;
    float* ls2 = yt + 64 * 32;
    ls1[tr * 32 + c0 + 0] = cs1[0]; ls1[tr * 32 + c0 + 1] = cs1[1];
    ls1[tr * 32 + c0 + 2] = cs1[2]; ls1[tr * 32 + c0 + 3] = cs1[3];
    ls2[tr * 32 + c0 + 0] = cs2[0]; ls2[tr * 32 + c0 + 1] = cs2[1];
    ls2[tr * 32 + c0 + 2] = cs2[2]; ls2[tr * 32 + c0 + 3] = cs2[3];
    __syncthreads();
    if (t < 32) {
        float a1 = 0.f, a2 = 0.f;
#pragma unroll
        for (int r = 0; r < 64; r++) { a1 += ls1[r * 32 + t]; a2 += ls2[r * 32 + t]; }
        atomicAdd(&st[t], (double)a1);
        atomicAdd(&st[32 + t], (double)a2);
    }
}

__global__ void bnprep1_kernel(const double* __restrict__ st,
                               const float* __restrict__ g, const float* __restrict__ be,
                               float* __restrict__ s1, float* __restrict__ t1, int E) {
    int c = threadIdx.x;
    if (c < 32) {
        double mu = st[c] / (double)E;
        double var = st[32 + c] / (double)E - mu * mu;
        double inv = 1.0 / sqrt(var + 1e-5);
        float s = (float)((double)g[c] * inv);
        float t = (float)((double)be[c] - (double)s * mu);
        s1[c] = s; t1[c] = t;
    }
}

// MLP layer 2 + sigmoid; z1 is in sorted order -> scatter out via esort
__global__ void mlp2_kernel(const float* __restrict__ z1, const int* __restrict__ esort,
                            const float* __restrict__ s1, const float* __restrict__ t1,
                            const float* __restrict__ Wm2, const float* __restrict__ bm2,
                            float* __restrict__ out, int E) {
    int pos = blockIdx.x * 256 + threadIdx.x;
    if (pos >= E) return;
    const float* zr = z1 + (size_t)pos * 32;
    float acc = bm2[0];
#pragma unroll
    for (int k = 0; k < 32; k += 4) {
        float4 z4 = *(const float4*)&zr[k];
        float4 sv = *(const float4*)&s1[k];
        float4 tv = *(const float4*)&t1[k];
        float4 wv = *(const float4*)&Wm2[k];
        acc += fmaxf(sv.x * z4.x + tv.x, 0.f) * wv.x;
        acc += fmaxf(sv.y * z4.y + tv.y, 0.f) * wv.y;
        acc += fmaxf(sv.z * z4.z + tv.z, 0.f) * wv.z;
        acc += fmaxf(sv.w * z4.w + tv.w, 0.f) * wv.w;
    }
    out[esort[pos]] = 1.f / (1.f + expf(-acc));
}

// ---------------------------------------------------------------------------
extern "C" void kernel_launch(void* const* d_in, const int* in_sizes, int n_in,
                              void* d_out, int out_size, void* d_ws, size_t ws_size,
                              hipStream_t stream) {
    const float* x      = (const float*)d_in[0];
    const int*   eidx   = (const int*)d_in[1];
    const float* W_emb  = (const float*)d_in[2];
    const float* b_emb  = (const float*)d_in[3];
    const float* W_g1   = (const float*)d_in[4];
    const float* b_g1   = (const float*)d_in[5];
    const float* W_g2   = (const float*)d_in[6];
    const float* b_g2   = (const float*)d_in[7];
    const float* W_m0   = (const float*)d_in[8];
    const float* b_m0   = (const float*)d_in[9];
    const float* g_m0   = (const float*)d_in[10];
    const float* be_m0  = (const float*)d_in[11];
    const float* W_m1   = (const float*)d_in[12];
    const float* b_m1   = (const float*)d_in[13];
    const float* g_m1   = (const float*)d_in[14];
    const float* be_m1  = (const float*)d_in[15];
    const float* W_m2   = (const float*)d_in[16];
    const float* b_m2   = (const float*)d_in[17];
    float* out = (float*)d_out;

    const int N = in_sizes[0] / IN_D;   // 50000
    const int E = in_sizes[1] / 2;      // 800000
    const int* src = eidx;
    const int* dst = eidx + E;

    char* p = (char*)d_ws;
    auto alloc = [&](size_t bytes) {
        void* r = (void*)p;
        p += (bytes + 255) & ~(size_t)255;
        return r;
    };
    int*    hist   = (int*)alloc((size_t)N * 4);            // in-degree (raw)
    int*    odeg   = (int*)alloc((size_t)N * 4);            // out-degree (raw)
    int*    rowptr = (int*)alloc((size_t)(N + 1) * 4);
    int*    cursor = (int*)alloc((size_t)N * 4);
    int*    bsum   = (int*)alloc(256 * 4);                  // block sums for scan
    int*    ssort  = (int*)alloc((size_t)E * 4);
    int*    dsort  = (int*)alloc((size_t)E * 4);
    int*    esort  = (int*)alloc((size_t)E * 4);
    float*  dinv   = (float*)alloc((size_t)N * 4);
    float*  B2     = (float*)alloc((size_t)N * HIDD * 4);   // h0, later agg2
    float*  B3     = (float*)alloc((size_t)N * HIDD * 4);   // hW1, later hW2
    float*  B4     = (float*)alloc((size_t)N * HIDD * 4);   // agg1, later AB
    float*  z1     = (float*)alloc((size_t)E * 32 * 4);
    float*  Wc     = (float*)alloc(64 * 128 * 4);
    double* dsum   = (double*)alloc(256 * 8);               // S1|S2|X|st1
    float*  s0     = (float*)alloc(64 * 4);
    float*  t0     = (float*)alloc(64 * 4);
    float*  s1v    = (float*)alloc(32 * 4);
    float*  t1v    = (float*)alloc(32 * 4);

    double* dS1 = dsum;
    double* dS2 = dsum + 64;
    double* dX  = dsum + 128;
    double* st1 = dsum + 192;

    float* h0   = B2;  float* agg2 = B2;
    float* hW1  = B3;  float* hW2  = B3;
    float* agg1 = B4;  float* AB   = B4;

    const int nbE = (E + 255) / 256;
    const int nbN = (N + 255) / 256;   // 196

    // CSR build (dst-sorted) + degrees + dinv — parallel 3-phase scan
    init_kernel<<<nbN, 256, 0, stream>>>(hist, odeg, dsum, N);
    hist_kernel<<<nbE, 256, 0, stream>>>(src, dst, hist, odeg, E);
    blocksum_kernel<<<nbN, 256, 0, stream>>>(hist, bsum, N);
    scanb_kernel<<<1, 256, 0, stream>>>(bsum, nbN);
    prefix_kernel<<<nbN, 256, 0, stream>>>(hist, bsum, rowptr, cursor, dinv, N, E);
    fill_kernel<<<nbE, 256, 0, stream>>>(src, dst, cursor, ssort, dsort, esort, E);

    // embedding: h0 = x @ W_emb + b_emb
    mm_kernel<256, 128, false, true><<<(N + 63) / 64, 512, 0, stream>>>(x, W_emb, b_emb, h0, N);

    // GCN1
    mm_kernel<128, 128, false, false><<<(N + 63) / 64, 512, 0, stream>>>(h0, W_g1, nullptr, hW1, N);
    agg_kernel<128><<<(N + 7) / 8, 256, 0, stream>>>(hW1, dinv, rowptr, ssort, b_g1, agg1, N);

    // GCN2 (relu on agg1 fused into GEMM staging)
    mm_kernel<128, 64, true, false><<<(N + 63) / 64, 256, 0, stream>>>(agg1, W_g2, nullptr, hW2, N);
    agg_kernel<64><<<(N + 15) / 16, 256, 0, stream>>>(hW2, dinv, rowptr, ssort, b_g2, agg2, N);

    // AB = h2 @ [Wtop|Wbot]  (edge MLP layer-0 factorization)
    concat_w_kernel<<<32, 256, 0, stream>>>(W_m0, Wc);
    mm_kernel<64, 128, false, false><<<(N + 63) / 64, 512, 0, stream>>>(agg2, Wc, nullptr, AB, N);

    // BN0 stats via node-level algebra (no O(E) edge pass)
    bn0_node_kernel<<<512, 256, 0, stream>>>(AB, hist, odeg, rowptr, ssort, dS1, dS2, dX, N);
    bnprep0_kernel<<<1, 64, 0, stream>>>(dS1, dS2, dX, g_m0, be_m0, b_m0, s0, t0, E);

    // MLP1 (edge-tile GEMM, split-K staging) -> z1 (sorted order), BN1 stats fused
    mlp1_fused_kernel<<<(E + 255) / 256, 512, 0, stream>>>(AB, ssort, dsort, b_m0,
                                                           s0, t0, W_m1, b_m1, z1, st1, E);
    bnprep1_kernel<<<1, 32, 0, stream>>>(st1, g_m1, be_m1, s1v, t1v, E);

    // MLP2 + sigmoid, scatter to original edge order
    mlp2_kernel<<<nbE, 256, 0, stream>>>(z1, esort, s1v, t1v, W_m2, b_m2, out, E);
}